// Round 2
// baseline (2409.704 us; speedup 1.0000x reference)
//
#include <hip/hip_runtime.h>

#define B_ 64
#define T_ 20
#define C_ 2048
#define R_ 49
#define H_ 512
#define E_ 256
#define VOC_ 32000

struct P {
  const float *feat, *W_a, *b_a, *W_b, *b_b, *embed, *Wv, *Wg, *Wh;
  const float *W_ih, *W_hh, *b_ih, *b_hh, *W_mlp, *b_mlp;
  const int *captions;
  float *Xt, *a_g, *v_g, *V, *V_proj, *h, *c, *hid, *gpart, *out;
  int t;
};

__device__ __forceinline__ float wsum(float v){
  #pragma unroll
  for (int o=32;o;o>>=1) v += __shfl_xor(v,o);
  return v;
}
__device__ __forceinline__ float wmax(float v){
  #pragma unroll
  for (int o=32;o;o>>=1) v = fmaxf(v,__shfl_xor(v,o));
  return v;
}
__device__ __forceinline__ float sigmoidf_(float x){ return 1.f/(1.f+expf(-x)); }

// ---------------------------------------------------------------------------
// K0: feat [B,C,7,7] -> Xt [B,R,C] (in d_out scratch) + a_g[b][c]=mean_r feat
// ---------------------------------------------------------------------------
__global__ __launch_bounds__(256) void transpose_k(P p){
  __shared__ float sm[32*R_];
  int b = blockIdx.x, c0 = blockIdx.y*32, tid = threadIdx.x;
  const float* src = p.feat + (size_t)(b*C_ + c0)*R_;
  for (int i=tid; i<32*R_; i+=256) sm[i]=src[i];
  __syncthreads();
  if (tid<32){
    float s=0.f;
    #pragma unroll
    for (int r=0;r<R_;r++) s += sm[tid*R_+r];
    p.a_g[b*C_ + c0 + tid] = s*(1.f/49.f);
  }
  for (int i=tid; i<32*R_; i+=256){
    int r=i>>5, cc=i&31;
    p.Xt[(size_t)(b*R_+r)*C_ + c0+cc] = sm[cc*R_+r];
  }
}

// ---------------------------------------------------------------------------
// generic 64x64-tile f32 GEMM, BK=16, 256 thr, 4x4 micro-tile.
// MODE 0: v_g = relu(a_g @ W_b^T + b_b)         M=64  N=512  K=2048
// MODE 1: V   = relu(Xt  @ W_a^T + b_a)         M=3136 N=512 K=2048
// MODE 2: V_proj = V @ Wv^T                     M=3136 N=49  K=512
// MODE 3: gates partials = [ct,emb,h] @ [Wih|Whh]^T   M=64 N=2048 K=1280, splitK=8x160
// ---------------------------------------------------------------------------
template<int MODE>
__device__ __forceinline__ float4 loadA(const P& p, int m, int k){
  if (MODE==0) return *(const float4*)&p.a_g[(size_t)m*C_+k];
  if (MODE==1) return *(const float4*)&p.Xt[(size_t)m*C_+k];
  if (MODE==2) return *(const float4*)&p.V[(size_t)m*H_+k];
  // MODE 3: concat [ c_t (512) | embed (256) | h (512) ]  -> K=1280
  if (k < H_)      return *(const float4*)&p.hid[(size_t)(m*T_+p.t)*1024 + k];
  if (k < H_+E_)   return *(const float4*)&p.embed[(size_t)p.captions[m*T_+p.t]*E_ + (k-H_)];
  return *(const float4*)&p.h[(size_t)m*H_ + (k-H_-E_)];
}
template<int MODE>
__device__ __forceinline__ float4 loadB(const P& p, int n, int k){
  if (MODE==0) return *(const float4*)&p.W_b[(size_t)n*C_+k];
  if (MODE==1) return *(const float4*)&p.W_a[(size_t)n*C_+k];
  if (MODE==2) { if (n<R_) return *(const float4*)&p.Wv[(size_t)n*H_+k]; return float4{0.f,0.f,0.f,0.f}; }
  if (k < 768) return *(const float4*)&p.W_ih[(size_t)n*768 + k];
  return *(const float4*)&p.W_hh[(size_t)n*H_ + (k-768)];
}

template<int MODE>
__global__ __launch_bounds__(256) void gemm64_k(P p){
  constexpr int K = (MODE==2)?512 : (MODE==3)?1280 : 2048;
  __shared__ float As[16][68], Bs[16][68];
  int tid=threadIdx.x;
  int m0=blockIdx.x*64, n0=blockIdx.y*64;
  int row=tid>>2, kq=(tid&3)<<2;
  int tx=tid&15, ty=tid>>4;
  int kb=0, ke=K;
  if (MODE==3){ kb=blockIdx.z*160; ke=kb+160; }
  float acc[4][4]={};
  for (int k0=kb; k0<ke; k0+=16){
    float4 av = loadA<MODE>(p, m0+row, k0+kq);
    float4 bv = loadB<MODE>(p, n0+row, k0+kq);
    As[kq+0][row]=av.x; As[kq+1][row]=av.y; As[kq+2][row]=av.z; As[kq+3][row]=av.w;
    Bs[kq+0][row]=bv.x; Bs[kq+1][row]=bv.y; Bs[kq+2][row]=bv.z; Bs[kq+3][row]=bv.w;
    __syncthreads();
    #pragma unroll
    for (int kk=0;kk<16;kk++){
      float a4[4], b4[4];
      #pragma unroll
      for (int i=0;i<4;i++){ a4[i]=As[kk][ty*4+i]; b4[i]=Bs[kk][tx*4+i]; }
      #pragma unroll
      for (int i=0;i<4;i++)
        #pragma unroll
        for (int j=0;j<4;j++) acc[i][j] += a4[i]*b4[j];
    }
    __syncthreads();
  }
  if (MODE==3){
    float* dst = p.gpart + (size_t)blockIdx.z*64*2048;
    #pragma unroll
    for (int i=0;i<4;i++){
      int m=ty*4+i;
      #pragma unroll
      for (int j=0;j<4;j++) dst[(size_t)m*2048 + n0+tx*4+j] = acc[i][j];
    }
  } else {
    #pragma unroll
    for (int i=0;i<4;i++){
      int m=m0+ty*4+i;
      #pragma unroll
      for (int j=0;j<4;j++){
        int n=n0+tx*4+j;
        float v=acc[i][j];
        if (MODE==0){ v+=p.b_b[n]; v=fmaxf(v,0.f); p.v_g[(size_t)m*H_+n]=v; }
        if (MODE==1){ v+=p.b_a[n]; v=fmaxf(v,0.f); p.V[(size_t)m*H_+n]=v; }
        if (MODE==2){ if (n<R_) p.V_proj[(size_t)m*R_+n]=v; }
      }
    }
  }
}

// ---------------------------------------------------------------------------
// init: h = c = v_g
// ---------------------------------------------------------------------------
__global__ __launch_bounds__(256) void init_k(P p){
  int idx = blockIdx.x*256+threadIdx.x;           // 32768 = 64*512
  float v = p.v_g[idx];
  p.h[idx]=v; p.c[idx]=v;
}

// ---------------------------------------------------------------------------
// attention, one block per batch b: z/softmax over 49 regions, c_t = alpha@V
// writes c_t -> hid[b][t][0:512]
// ---------------------------------------------------------------------------
__global__ __launch_bounds__(256) void att_k(P p){
  int b = blockIdx.x, tid = threadIdx.x;
  __shared__ float hs[H_], gv[R_], zs[R_], as_[R_];
  hs[tid]       = p.h[(size_t)b*H_ + tid];
  hs[tid+256]   = p.h[(size_t)b*H_ + tid + 256];
  __syncthreads();
  // gv[k] = sum_h h[b][h]*Wg[k][h] ; 4 lanes per k
  if (tid < R_*4){
    int k=tid>>2, part=tid&3;
    const float* wg = p.Wg + (size_t)k*H_ + part*128;
    const float* hh = hs + part*128;
    float s=0.f;
    #pragma unroll 8
    for (int i=0;i<128;i++) s += hh[i]*wg[i];
    s += __shfl_xor(s,1); s += __shfl_xor(s,2);
    if (part==0) gv[k]=s;
  }
  __syncthreads();
  int lane=tid&63, wid=tid>>6;
  // z[r] = sum_k tanh(V_proj[b,r,k]+gv[k]) * wh[k]
  for (int r=wid; r<R_; r+=4){
    float v=0.f;
    if (lane<R_) v = tanhf(p.V_proj[(size_t)(b*R_+r)*R_ + lane] + gv[lane]) * p.Wh[lane];
    v = wsum(v);
    if (lane==0) zs[r]=v;
  }
  __syncthreads();
  if (wid==0){
    float z = (lane<R_)? zs[lane] : -1e30f;
    float m = wmax(z);
    float e = (lane<R_)? expf(zs[lane]-m) : 0.f;
    float s = wsum(e);
    if (lane<R_) as_[lane]=e/s;
  }
  __syncthreads();
  float* ct = p.hid + (size_t)(b*T_ + p.t)*1024;
  for (int hh=tid; hh<H_; hh+=256){
    float acc=0.f;
    #pragma unroll 7
    for (int r=0;r<R_;r++) acc += as_[r]*p.V[(size_t)(b*R_+r)*H_ + hh];
    ct[hh]=acc;
  }
}

// ---------------------------------------------------------------------------
// LSTM pointwise: reduce 8 gate partials + biases, update h/c, write h_new
// ---------------------------------------------------------------------------
__global__ __launch_bounds__(256) void point_k(P p){
  int idx = blockIdx.x*256+threadIdx.x;           // 32768 = 64*512
  int b=idx>>9, hh=idx&511;
  float g4[4];
  #pragma unroll
  for (int g=0; g<4; g++){
    int col = g*512 + hh;
    float s = p.b_ih[col] + p.b_hh[col];
    #pragma unroll
    for (int z=0; z<8; z++) s += p.gpart[(size_t)(z*64+b)*2048 + col];
    g4[g]=s;
  }
  float cn = sigmoidf_(g4[1])*p.c[idx] + sigmoidf_(g4[0])*tanhf(g4[2]);
  float hn = sigmoidf_(g4[3])*tanhf(cn);
  p.c[idx]=cn; p.h[idx]=hn;
  p.hid[(size_t)(b*T_ + p.t)*1024 + H_ + hh] = hn;
}

// ---------------------------------------------------------------------------
// final MLP: scores = hid[1280,1024] @ W_mlp^T[1024,32000] + b_mlp
// 128x128 tile, 8x8 micro, BK=16
// ---------------------------------------------------------------------------
__global__ __launch_bounds__(256) void mlp_k(P p){
  __shared__ float As[16][132], Bs[16][132];
  int tid=threadIdx.x;
  int m0=blockIdx.x*128, n0=blockIdx.y*128;
  int row=tid>>2, kq=(tid&3)<<2;
  int tx=tid&15, ty=tid>>4;
  float acc[8][8]={};
  for (int k0=0;k0<1024;k0+=16){
    #pragma unroll
    for (int hf=0; hf<2; hf++){
      int r=row+hf*64;
      float4 av = *(const float4*)&p.hid  [(size_t)(m0+r)*1024 + k0+kq];
      float4 bv = *(const float4*)&p.W_mlp[(size_t)(n0+r)*1024 + k0+kq];
      As[kq+0][r]=av.x; As[kq+1][r]=av.y; As[kq+2][r]=av.z; As[kq+3][r]=av.w;
      Bs[kq+0][r]=bv.x; Bs[kq+1][r]=bv.y; Bs[kq+2][r]=bv.z; Bs[kq+3][r]=bv.w;
    }
    __syncthreads();
    #pragma unroll
    for (int kk=0;kk<16;kk++){
      float a8[8], b8[8];
      #pragma unroll
      for (int i=0;i<8;i++){ a8[i]=As[kk][ty*8+i]; b8[i]=Bs[kk][tx*8+i]; }
      #pragma unroll
      for (int i=0;i<8;i++)
        #pragma unroll
        for (int j=0;j<8;j++) acc[i][j] += a8[i]*b8[j];
    }
    __syncthreads();
  }
  #pragma unroll
  for (int i=0;i<8;i++){
    int m=m0+ty*8+i;
    #pragma unroll
    for (int j=0;j<8;j++){
      int n=n0+tx*8+j;
      p.out[(size_t)m*VOC_ + n] = acc[i][j] + p.b_mlp[n];
    }
  }
}

// ---------------------------------------------------------------------------
extern "C" void kernel_launch(void* const* d_in, const int* in_sizes, int n_in,
                              void* d_out, int out_size, void* d_ws, size_t ws_size,
                              hipStream_t stream) {
  P p;
  p.feat     = (const float*)d_in[0];
  p.captions = (const int*)  d_in[1];
  // d_in[2] = lengths (unused: all T)
  p.W_a   = (const float*)d_in[3];
  p.b_a   = (const float*)d_in[4];
  p.W_b   = (const float*)d_in[5];
  p.b_b   = (const float*)d_in[6];
  p.embed = (const float*)d_in[7];
  p.Wv    = (const float*)d_in[8];
  p.Wg    = (const float*)d_in[9];
  p.Wh    = (const float*)d_in[10];
  p.W_ih  = (const float*)d_in[11];
  p.W_hh  = (const float*)d_in[12];
  p.b_ih  = (const float*)d_in[13];
  p.b_hh  = (const float*)d_in[14];
  p.W_mlp = (const float*)d_in[15];
  p.b_mlp = (const float*)d_in[16];

  float* ws = (float*)d_ws;
  p.a_g    = ws;                 // 64*2048            = 131072
  p.v_g    = ws + 131072;        // 64*512             = 32768
  p.V      = ws + 163840;        // 64*49*512          = 1605632
  p.V_proj = ws + 1769472;       // 64*49*49           = 153664
  p.h      = ws + 1923136;       // 64*512
  p.c      = ws + 1955904;       // 64*512
  p.hid    = ws + 1988672;       // 64*20*1024         = 1310720
  p.gpart  = ws + 3299392;       // 8*64*2048          = 1048576  (total ~16.6MB)
  p.Xt     = (float*)d_out;      // 64*49*2048 scratch in d_out (overwritten by mlp_k)
  p.out    = (float*)d_out;
  p.t      = 0;

  transpose_k<<<dim3(64,64),256,0,stream>>>(p);       // Xt + a_g
  gemm64_k<0><<<dim3(1,8)  ,256,0,stream>>>(p);       // v_g
  gemm64_k<1><<<dim3(49,8) ,256,0,stream>>>(p);       // V
  gemm64_k<2><<<dim3(49,1) ,256,0,stream>>>(p);       // V_proj
  init_k     <<<128        ,256,0,stream>>>(p);       // h=c=v_g

  for (int t=0;t<T_;t++){
    p.t=t;
    att_k      <<<64           ,256,0,stream>>>(p);   // alpha, c_t -> hid[:,t,0:512]
    gemm64_k<3><<<dim3(1,32,8) ,256,0,stream>>>(p);   // gate partials (splitK=8x160)
    point_k    <<<128          ,256,0,stream>>>(p);   // LSTM update -> hid[:,t,512:1024]
  }

  mlp_k<<<dim3(10,250),256,0,stream>>>(p);            // scores
}

// Round 3
// 1555.905 us; speedup vs baseline: 1.5487x; 1.5487x over previous
//
#include <hip/hip_runtime.h>

#define B_ 64
#define T_ 20
#define C_ 2048
#define R_ 49
#define H_ 512
#define E_ 256
#define VOC_ 32000

typedef __attribute__((ext_vector_type(8))) short short8;
typedef __attribute__((ext_vector_type(4))) float f32x4;

struct P {
  const float *feat, *W_a, *b_a, *W_b, *b_b, *embed, *Wv, *Wg, *Wh;
  const float *W_ih, *W_hh, *b_ih, *b_hh, *W_mlp, *b_mlp;
  const int *captions;
  float *Xt, *a_g, *v_g, *V, *V_proj, *h, *c, *hid, *gpart, *epj, *out;
  int t;
};

__device__ __forceinline__ float wsum(float v){
  #pragma unroll
  for (int o=32;o;o>>=1) v += __shfl_xor(v,o);
  return v;
}
__device__ __forceinline__ float wmax(float v){
  #pragma unroll
  for (int o=32;o;o>>=1) v = fmaxf(v,__shfl_xor(v,o));
  return v;
}
__device__ __forceinline__ float sigmoidf_(float x){ return 1.f/(1.f+expf(-x)); }
__device__ __forceinline__ unsigned short f2bf(float f){
  unsigned u = __builtin_bit_cast(unsigned, f);
  unsigned r = u + 0x7FFFu + ((u>>16)&1u);
  return (unsigned short)(r>>16);
}

// ---------------------------------------------------------------------------
// K0: feat [B,C,7,7] -> Xt [B,R,C] (in d_out scratch) + a_g[b][c]=mean_r feat
// ---------------------------------------------------------------------------
__global__ __launch_bounds__(256) void transpose_k(P p){
  __shared__ float sm[32*R_];
  int b = blockIdx.x, c0 = blockIdx.y*32, tid = threadIdx.x;
  const float* src = p.feat + (size_t)(b*C_ + c0)*R_;
  for (int i=tid; i<32*R_; i+=256) sm[i]=src[i];
  __syncthreads();
  if (tid<32){
    float s=0.f;
    #pragma unroll
    for (int r=0;r<R_;r++) s += sm[tid*R_+r];
    p.a_g[b*C_ + c0 + tid] = s*(1.f/49.f);
  }
  for (int i=tid; i<32*R_; i+=256){
    int r=i>>5, cc=i&31;
    p.Xt[(size_t)(b*R_+r)*C_ + c0+cc] = sm[cc*R_+r];
  }
}

// ---------------------------------------------------------------------------
// generic 64x64-tile f32 GEMM, BK=16, 256 thr, 4x4 micro-tile.
// MODE 0: v_g = relu(a_g @ W_b^T + b_b)         M=64  N=512  K=2048
// MODE 1: V   = relu(Xt  @ W_a^T + b_a)         M=3136 N=512 K=2048
// MODE 2: V_proj = V @ Wv^T                     M=3136 N=49  K=512
// MODE 3: gates partials = [ct,h] @ [Wih_c|Whh]^T  M=64 N=2048 K=1024 splitK 8x128
// MODE 4: epj = emb @ W_ih[:,512:768]^T         M=1280 N=2048 K=256
// ---------------------------------------------------------------------------
template<int MODE>
__device__ __forceinline__ float4 loadA(const P& p, int m, int k){
  if (MODE==0) return *(const float4*)&p.a_g[(size_t)m*C_+k];
  if (MODE==1) return *(const float4*)&p.Xt[(size_t)m*C_+k];
  if (MODE==2) return *(const float4*)&p.V[(size_t)m*H_+k];
  if (MODE==4) return *(const float4*)&p.embed[(size_t)p.captions[m]*E_ + k];
  // MODE 3: concat [ c_t (512) | h (512) ]
  if (k < H_)  return *(const float4*)&p.hid[(size_t)(m*T_+p.t)*1024 + k];
  return *(const float4*)&p.h[(size_t)m*H_ + (k-H_)];
}
template<int MODE>
__device__ __forceinline__ float4 loadB(const P& p, int n, int k){
  if (MODE==0) return *(const float4*)&p.W_b[(size_t)n*C_+k];
  if (MODE==1) return *(const float4*)&p.W_a[(size_t)n*C_+k];
  if (MODE==2) { if (n<R_) return *(const float4*)&p.Wv[(size_t)n*H_+k]; return float4{0.f,0.f,0.f,0.f}; }
  if (MODE==4) return *(const float4*)&p.W_ih[(size_t)n*768 + 512 + k];
  // MODE 3
  if (k < H_)  return *(const float4*)&p.W_ih[(size_t)n*768 + k];
  return *(const float4*)&p.W_hh[(size_t)n*H_ + (k-H_)];
}

template<int MODE>
__global__ __launch_bounds__(256) void gemm64_k(P p){
  constexpr int K = (MODE==2)?512 : (MODE==3)?1024 : (MODE==4)?256 : 2048;
  __shared__ float As[16][68], Bs[16][68];
  int tid=threadIdx.x;
  int m0=blockIdx.x*64, n0=blockIdx.y*64;
  int row=tid>>2, kq=(tid&3)<<2;
  int tx=tid&15, ty=tid>>4;
  int kb=0, ke=K;
  if (MODE==3){ kb=blockIdx.z*128; ke=kb+128; }
  float acc[4][4]={};
  for (int k0=kb; k0<ke; k0+=16){
    float4 av = loadA<MODE>(p, m0+row, k0+kq);
    float4 bv = loadB<MODE>(p, n0+row, k0+kq);
    As[kq+0][row]=av.x; As[kq+1][row]=av.y; As[kq+2][row]=av.z; As[kq+3][row]=av.w;
    Bs[kq+0][row]=bv.x; Bs[kq+1][row]=bv.y; Bs[kq+2][row]=bv.z; Bs[kq+3][row]=bv.w;
    __syncthreads();
    #pragma unroll
    for (int kk=0;kk<16;kk++){
      float a4[4], b4[4];
      #pragma unroll
      for (int i=0;i<4;i++){ a4[i]=As[kk][ty*4+i]; b4[i]=Bs[kk][tx*4+i]; }
      #pragma unroll
      for (int i=0;i<4;i++)
        #pragma unroll
        for (int j=0;j<4;j++) acc[i][j] += a4[i]*b4[j];
    }
    __syncthreads();
  }
  if (MODE==3){
    float* dst = p.gpart + (size_t)blockIdx.z*64*2048;
    #pragma unroll
    for (int i=0;i<4;i++){
      int m=ty*4+i;
      #pragma unroll
      for (int j=0;j<4;j++) dst[(size_t)m*2048 + n0+tx*4+j] = acc[i][j];
    }
  } else {
    #pragma unroll
    for (int i=0;i<4;i++){
      int m=m0+ty*4+i;
      #pragma unroll
      for (int j=0;j<4;j++){
        int n=n0+tx*4+j;
        float v=acc[i][j];
        if (MODE==0){ v+=p.b_b[n]; v=fmaxf(v,0.f); p.v_g[(size_t)m*H_+n]=v; }
        if (MODE==1){ v+=p.b_a[n]; v=fmaxf(v,0.f); p.V[(size_t)m*H_+n]=v; }
        if (MODE==2){ if (n<R_) p.V_proj[(size_t)m*R_+n]=v; }
        if (MODE==4){ p.epj[(size_t)m*2048+n]=v; }
      }
    }
  }
}

// ---------------------------------------------------------------------------
// init: h = c = v_g
// ---------------------------------------------------------------------------
__global__ __launch_bounds__(256) void init_k(P p){
  int idx = blockIdx.x*256+threadIdx.x;           // 32768 = 64*512
  float v = p.v_g[idx];
  p.h[idx]=v; p.c[idx]=v;
}

// ---------------------------------------------------------------------------
// fused: [if t>0: LSTM pointwise of step t-1 -> h,c] + attention of step t.
// One block per batch b. Writes c_t -> hid[b][t][0:512], h -> hid[b][t-1][512:].
// ---------------------------------------------------------------------------
__global__ __launch_bounds__(256) void fused_att_k(P p){
  int b = blockIdx.x, tid = threadIdx.x;
  __shared__ float hs[H_], gv[R_], zs[R_], as_[R_];
  int t = p.t;

  if (t > 0){
    // LSTM pointwise for step t-1: thread handles h = tid and tid+256
    #pragma unroll
    for (int half=0; half<2; half++){
      int hx = tid + half*256;
      float g4[4];
      #pragma unroll
      for (int g=0; g<4; g++){
        int col = g*512 + hx;
        float s = p.b_ih[col] + p.b_hh[col]
                + p.epj[(size_t)(b*T_ + (t-1))*2048 + col];
        #pragma unroll
        for (int z=0; z<8; z++) s += p.gpart[(size_t)(z*64+b)*2048 + col];
        g4[g]=s;
      }
      int idx = b*H_ + hx;
      float cn = sigmoidf_(g4[1])*p.c[idx] + sigmoidf_(g4[0])*tanhf(g4[2]);
      float hn = sigmoidf_(g4[3])*tanhf(cn);
      p.c[idx]=cn; p.h[idx]=hn;
      p.hid[(size_t)(b*T_ + (t-1))*1024 + H_ + hx] = hn;
      hs[hx] = hn;
    }
  } else {
    hs[tid]     = p.h[(size_t)b*H_ + tid];
    hs[tid+256] = p.h[(size_t)b*H_ + tid + 256];
  }
  __syncthreads();

  // gv[k] = sum_h h[b][h]*Wg[k][h] ; 4 lanes per k
  if (tid < R_*4){
    int k=tid>>2, part=tid&3;
    const float* wg = p.Wg + (size_t)k*H_ + part*128;
    const float* hh = hs + part*128;
    float s=0.f;
    #pragma unroll 8
    for (int i=0;i<128;i++) s += hh[i]*wg[i];
    s += __shfl_xor(s,1); s += __shfl_xor(s,2);
    if (part==0) gv[k]=s;
  }
  __syncthreads();
  int lane=tid&63, wid=tid>>6;
  // z[r] = sum_k tanh(V_proj[b,r,k]+gv[k]) * wh[k]
  for (int r=wid; r<R_; r+=4){
    float v=0.f;
    if (lane<R_) v = tanhf(p.V_proj[(size_t)(b*R_+r)*R_ + lane] + gv[lane]) * p.Wh[lane];
    v = wsum(v);
    if (lane==0) zs[r]=v;
  }
  __syncthreads();
  if (wid==0){
    float z = (lane<R_)? zs[lane] : -1e30f;
    float m = wmax(z);
    float e = (lane<R_)? expf(zs[lane]-m) : 0.f;
    float s = wsum(e);
    if (lane<R_) as_[lane]=e/s;
  }
  __syncthreads();
  float* ct = p.hid + (size_t)(b*T_ + t)*1024;
  for (int hh=tid; hh<H_; hh+=256){
    float acc=0.f;
    #pragma unroll 7
    for (int r=0;r<R_;r++) acc += as_[r]*p.V[(size_t)(b*R_+r)*H_ + hh];
    ct[hh]=acc;
  }
}

// ---------------------------------------------------------------------------
// tail pointwise for t=19
// ---------------------------------------------------------------------------
__global__ __launch_bounds__(256) void point_tail_k(P p){
  int idx = blockIdx.x*256+threadIdx.x;           // 32768 = 64*512
  int b=idx>>9, hh=idx&511;
  float g4[4];
  #pragma unroll
  for (int g=0; g<4; g++){
    int col = g*512 + hh;
    float s = p.b_ih[col] + p.b_hh[col]
            + p.epj[(size_t)(b*T_ + 19)*2048 + col];
    #pragma unroll
    for (int z=0; z<8; z++) s += p.gpart[(size_t)(z*64+b)*2048 + col];
    g4[g]=s;
  }
  float cn = sigmoidf_(g4[1])*p.c[idx] + sigmoidf_(g4[0])*tanhf(g4[2]);
  float hn = sigmoidf_(g4[3])*tanhf(cn);
  p.hid[(size_t)(b*T_ + 19)*1024 + H_ + hh] = hn;
}

// ---------------------------------------------------------------------------
// final MLP via bf16 MFMA: scores = hid[1280,1024] @ W_mlp^T + b_mlp
// 128x128 tile, BK=32, 4 waves x (4x4) 16x16x32 fragments.
// f32 inputs converted to bf16 during reg-staged LDS fill.
// ---------------------------------------------------------------------------
__global__ __launch_bounds__(256) void mlp_mfma_k(P p){
  __shared__ short A_s[128*32];   // [128][32] bf16, row-major
  __shared__ short B_s[128*32];
  int tid = threadIdx.x;
  int lane = tid & 63, w = tid >> 6;
  int m0 = blockIdx.x*128, n0 = blockIdx.y*128;
  int wr = (w>>1)*64, wc = (w&1)*64;
  int srow = tid>>2, scol = (tid&3)*8;
  f32x4 acc[4][4] = {};

  for (int k0=0; k0<1024; k0+=32){
    // stage A and B: thread covers rows {srow, 64+srow}, 8 k-elems each
    #pragma unroll
    for (int s=0; s<2; s++){
      const float* ga = p.hid   + (size_t)(m0 + s*64 + srow)*1024 + k0 + scol;
      const float* gb = p.W_mlp + (size_t)(n0 + s*64 + srow)*1024 + k0 + scol;
      float4 ax = *(const float4*)ga, ay = *(const float4*)(ga+4);
      float4 bx = *(const float4*)gb, by = *(const float4*)(gb+4);
      short8 av, bv;
      av[0]=(short)f2bf(ax.x); av[1]=(short)f2bf(ax.y); av[2]=(short)f2bf(ax.z); av[3]=(short)f2bf(ax.w);
      av[4]=(short)f2bf(ay.x); av[5]=(short)f2bf(ay.y); av[6]=(short)f2bf(ay.z); av[7]=(short)f2bf(ay.w);
      bv[0]=(short)f2bf(bx.x); bv[1]=(short)f2bf(bx.y); bv[2]=(short)f2bf(bx.z); bv[3]=(short)f2bf(bx.w);
      bv[4]=(short)f2bf(by.x); bv[5]=(short)f2bf(by.y); bv[6]=(short)f2bf(by.z); bv[7]=(short)f2bf(by.w);
      *(short8*)&A_s[(s*64+srow)*32 + scol] = av;   // byte off = s*4096 + tid*16 (conflict-free)
      *(short8*)&B_s[(s*64+srow)*32 + scol] = bv;
    }
    __syncthreads();
    short8 af[4], bf[4];
    int fr = lane&15, kq = (lane>>4)*8;
    #pragma unroll
    for (int i=0;i<4;i++) af[i] = *(short8*)&A_s[(wr + i*16 + fr)*32 + kq];
    #pragma unroll
    for (int j=0;j<4;j++) bf[j] = *(short8*)&B_s[(wc + j*16 + fr)*32 + kq];
    #pragma unroll
    for (int i=0;i<4;i++)
      #pragma unroll
      for (int j=0;j<4;j++)
        acc[i][j] = __builtin_amdgcn_mfma_f32_16x16x32_bf16(af[i], bf[j], acc[i][j], 0, 0, 0);
    __syncthreads();
  }

  // epilogue: C layout col=lane&15, row=(lane>>4)*4+reg  [m89/m91-verified]
  int cr = (lane>>4)*4, cc = lane&15;
  #pragma unroll
  for (int i=0;i<4;i++){
    int mrow = m0 + wr + i*16 + cr;
    #pragma unroll
    for (int j=0;j<4;j++){
      int col = n0 + wc + j*16 + cc;
      float bias = p.b_mlp[col];
      #pragma unroll
      for (int r=0;r<4;r++)
        p.out[(size_t)(mrow+r)*VOC_ + col] = acc[i][j][r] + bias;
    }
  }
}

// ---------------------------------------------------------------------------
extern "C" void kernel_launch(void* const* d_in, const int* in_sizes, int n_in,
                              void* d_out, int out_size, void* d_ws, size_t ws_size,
                              hipStream_t stream) {
  P p;
  p.feat     = (const float*)d_in[0];
  p.captions = (const int*)  d_in[1];
  // d_in[2] = lengths (unused: all T)
  p.W_a   = (const float*)d_in[3];
  p.b_a   = (const float*)d_in[4];
  p.W_b   = (const float*)d_in[5];
  p.b_b   = (const float*)d_in[6];
  p.embed = (const float*)d_in[7];
  p.Wv    = (const float*)d_in[8];
  p.Wg    = (const float*)d_in[9];
  p.Wh    = (const float*)d_in[10];
  p.W_ih  = (const float*)d_in[11];
  p.W_hh  = (const float*)d_in[12];
  p.b_ih  = (const float*)d_in[13];
  p.b_hh  = (const float*)d_in[14];
  p.W_mlp = (const float*)d_in[15];
  p.b_mlp = (const float*)d_in[16];

  float* ws = (float*)d_ws;
  p.a_g    = ws;                 // 64*2048            = 131072
  p.v_g    = ws + 131072;        // 64*512             = 32768
  p.V      = ws + 163840;        // 64*49*512          = 1605632
  p.V_proj = ws + 1769472;       // 64*49*49           = 153664
  p.h      = ws + 1923136;       // 64*512
  p.c      = ws + 1955904;       // 64*512
  p.hid    = ws + 1988672;       // 64*20*1024         = 1310720
  p.gpart  = ws + 3299392;       // 8*64*2048          = 1048576  (total ~17.4MB)
  float* dof = (float*)d_out;
  p.Xt     = dof;                // 64*49*2048 = 6422528  (scratch, consumed by V GEMM)
  p.epj    = dof + 6422528;      // 1280*2048  = 2621440  (scratch, consumed in recurrence)
  p.out    = dof;
  p.t      = 0;

  transpose_k<<<dim3(64,64),256,0,stream>>>(p);       // Xt + a_g
  gemm64_k<0><<<dim3(1,8)  ,256,0,stream>>>(p);       // v_g
  gemm64_k<1><<<dim3(49,8) ,256,0,stream>>>(p);       // V
  gemm64_k<2><<<dim3(49,1) ,256,0,stream>>>(p);       // V_proj
  gemm64_k<4><<<dim3(20,32),256,0,stream>>>(p);       // epj (emb @ W_ih[:,512:768]^T)
  init_k     <<<128        ,256,0,stream>>>(p);       // h=c=v_g

  for (int t=0;t<T_;t++){
    p.t=t;
    fused_att_k<<<64           ,256,0,stream>>>(p);   // [point(t-1)] + attention(t)
    gemm64_k<3><<<dim3(1,32,8) ,256,0,stream>>>(p);   // gate partials (K=1024, splitK 8x128)
  }
  point_tail_k<<<128,256,0,stream>>>(p);              // finish t=19

  mlp_mfma_k<<<dim3(10,250),256,0,stream>>>(p);       // scores (bf16 MFMA)
}